// Round 4
// baseline (700.005 us; speedup 1.0000x reference)
//
#include <hip/hip_runtime.h>

typedef unsigned short ushort_t;
typedef short short8 __attribute__((ext_vector_type(8)));
typedef float f32x4 __attribute__((ext_vector_type(4)));
typedef unsigned short ushort4v __attribute__((ext_vector_type(4)));

// ---------- helpers ----------
__device__ __forceinline__ ushort_t f2bf(float f) {
    unsigned int u = __float_as_uint(f);
    u = (u + 0x7fffu + ((u >> 16) & 1u)) >> 16;
    return (ushort_t)u;
}

__device__ __forceinline__ void async16(void* lds, const void* g) {
    __builtin_amdgcn_global_load_lds(
        (const __attribute__((address_space(1))) unsigned int*)g,
        (__attribute__((address_space(3))) unsigned int*)lds, 16, 0, 0);
}

// ---------- prep kernels ----------
__global__ void conv_x_kernel(const float* __restrict__ in, ushort_t* __restrict__ out) {
    int i = blockIdx.x * 256 + threadIdx.x;      // grid sized exactly: 50176*256 = 12845056
    float4 v = ((const float4*)in)[i];
    ushort4v o;
    o.x = f2bf(v.x); o.y = f2bf(v.y); o.z = f2bf(v.z); o.w = f2bf(v.w);
    ((ushort4v*)out)[i] = o;
}

__global__ void prep_weights(const float* __restrict__ qkv_w, const float* __restrict__ proj_w,
                             ushort_t* __restrict__ wtq, ushort_t* __restrict__ wtp) {
    int o = blockIdx.x * 256 + threadIdx.x;      // grid 3072*256 = 786432
    if (o < 1536 * 512) {
        int n = o >> 9, k = o & 511;
        wtq[o] = f2bf(qkv_w[k * 1536 + n]);      // wtq[n][k] = W[k][n]
    }
    if (o < 512 * 512) {
        int n = o >> 9, k = o & 511;
        wtp[o] = f2bf(proj_w[k * 512 + n]);
    }
}

__global__ void build_cm(const float* __restrict__ mask, const float* __restrict__ rel_table,
                         const int* __restrict__ rel_index, float* __restrict__ cm) {
    int o = blockIdx.x * 256 + threadIdx.x;      // grid 16384*256 = 4194304 = 64*16*64*64
    int c = o & 63, r = (o >> 6) & 63, h = (o >> 12) & 15, w = o >> 16;
    float v = -30000.0f;
    if (r < 49 && c < 49)
        v = rel_table[rel_index[r * 49 + c] * 16 + h] + mask[w * 2401 + r * 49 + c];
    cm[o] = v;
}

// ---------- 256x256 8-phase bf16 MFMA GEMM ----------
// C[M][N] = A[M][K] * Bt[N][K]^T + bias. BM=BN=256, BK=64, 8 waves (2M x 4N),
// double-buffered LDS (128 KiB, 1 block/CU).
// RACE-FREE STAGE SCHEDULE (fixes r3): every phase of buf X is read by some
// wave in ALL of its 4 phases (wave rows/cols span both halves), so buf0 is
// writable only after the phase-4 end barrier and buf1 after the phase-8 end
// barrier. Hence: phases 1-2 stage ALL of buf1 (tile 2i+1; buf1 freed at end
// of previous iteration), phases 5-6 stage ALL of buf0 (tile 2i+2). vmcnt(0)
// waits sit at phases 4 and 8, >= 2 phases after the last issue (issue-early).
// LDS swizzle: 16B-chunk XOR by (row>>1)&3 on the GLOBAL source and on the
// ds_read address (both sides, rule 21) -> measured-zero bank conflicts (r2).

#define STAGE(ldsbase, gbase) do {                                              \
    _Pragma("unroll")                                                           \
    for (int j_ = 0; j_ < 2; ++j_) {                                            \
        const int idx_ = j_ * 512 + tid;                                        \
        const int row_ = idx_ >> 3;                                             \
        const int c0_  = (idx_ & 7) << 3;                                       \
        const int sc_  = c0_ ^ (((row_ >> 1) & 3) << 3);                        \
        async16((char*)(ldsbase) + idx_ * 16, (gbase) + (size_t)row_ * K + sc_);\
    }                                                                           \
} while (0)

#define VMNOP ((void)0)
#define VM0 asm volatile("s_waitcnt vmcnt(0)" ::: "memory")
#define NOSTAGE ((void)0)

#define PHASE(buf, mh, nh, WAITST, ...) do {                                    \
    short8 af_[4][2], bf_[2][2];                                                \
    _Pragma("unroll")                                                           \
    for (int f_ = 0; f_ < 4; ++f_) {                                            \
        const int ar_ = wr + ((mh) * 4 + f_) * 16 + lr;                         \
        _Pragma("unroll")                                                       \
        for (int ks_ = 0; ks_ < 2; ++ks_)                                       \
            af_[f_][ks_] = *(const short8*)&As[buf][ar_ * 64 + ((ks_ * 32 + lk * 8) ^ swz)]; \
    }                                                                           \
    _Pragma("unroll")                                                           \
    for (int g_ = 0; g_ < 2; ++g_) {                                            \
        const int br_ = wc + ((nh) * 2 + g_) * 16 + lr;                         \
        _Pragma("unroll")                                                       \
        for (int ks_ = 0; ks_ < 2; ++ks_)                                       \
            bf_[g_][ks_] = *(const short8*)&Bs[buf][br_ * 64 + ((ks_ * 32 + lk * 8) ^ swz)]; \
    }                                                                           \
    __VA_ARGS__;                                                                \
    __builtin_amdgcn_s_barrier();                                               \
    asm volatile("s_waitcnt lgkmcnt(0)" ::: "memory");                          \
    __builtin_amdgcn_sched_barrier(0);                                          \
    __builtin_amdgcn_s_setprio(1);                                              \
    _Pragma("unroll")                                                           \
    for (int f_ = 0; f_ < 4; ++f_)                                              \
        _Pragma("unroll")                                                       \
        for (int g_ = 0; g_ < 2; ++g_)                                          \
            _Pragma("unroll")                                                   \
            for (int ks_ = 0; ks_ < 2; ++ks_)                                   \
                acc[(mh) * 4 + f_][(nh) * 2 + g_] = __builtin_amdgcn_mfma_f32_16x16x32_bf16( \
                    bf_[g_][ks_], af_[f_][ks_], acc[(mh) * 4 + f_][(nh) * 2 + g_], 0, 0, 0); \
    __builtin_amdgcn_s_setprio(0);                                              \
    WAITST;                                                                     \
    __builtin_amdgcn_s_barrier();                                               \
} while (0)

template<int NB_N, int NSTR, bool QKV, int K>
__global__ __launch_bounds__(512, 2)
void gemm8(const ushort_t* __restrict__ A, const ushort_t* __restrict__ Bt,
           const float* __restrict__ bias, void* __restrict__ out)
{
    __shared__ alignas(16) ushort_t As[2][256 * 64];   // 64 KiB
    __shared__ alignas(16) ushort_t Bs[2][256 * 64];   // 64 KiB

    const int tid = threadIdx.x;
    const int wid = tid >> 6, lane = tid & 63;
    const int lr = lane & 15, lk = lane >> 4;
    const int wr = (wid >> 2) * 128;     // 0 / 128
    const int wc = (wid & 3) * 64;       // 0..192
    const int swz = ((lr >> 1) & 3) << 3;

    // XCD-aware bijective swizzle (grid % 8 == 0 for both GEMMs)
    const int chunk = gridDim.x >> 3;
    const int wg = ((int)blockIdx.x & 7) * chunk + ((int)blockIdx.x >> 3);
    const int nb = wg % NB_N;
    const int mb = wg / NB_N;
    const int m0 = mb << 8, n0 = nb << 8;

    const size_t a0 = (size_t)m0 * K;
    const size_t a1 = (size_t)(m0 + 128) * K;
    const size_t b0 = (size_t)n0 * K;
    const size_t b1 = (size_t)(n0 + 128) * K;

    f32x4 acc[8][4];
#pragma unroll
    for (int f = 0; f < 8; ++f)
#pragma unroll
        for (int g = 0; g < 4; ++g)
#pragma unroll
            for (int r = 0; r < 4; ++r) acc[f][g][r] = 0.f;

    // prologue: tile0 -> buf0, drain, barrier
    STAGE(&As[0][0],    A  + a0);
    STAGE(&As[0][8192], A  + a1);
    STAGE(&Bs[0][0],    Bt + b0);
    STAGE(&Bs[0][8192], Bt + b1);
    VM0;
    __builtin_amdgcn_s_barrier();

    const int NI = K >> 7;   // tile pairs; NI=4 for K=512
    for (int i = 0; i < NI; ++i) {
        const int ck = (2 * i + 1) << 6;   // K-offset of tile for buf1 (read this iter, ph 5-8)
        const int cn = (2 * i + 2) << 6;   // K-offset of tile for buf0 (read next iter)
        const bool more = (i < NI - 1);
        // phases 1-4: read buf0 (tile 2i); stage buf1 (freed at end of prev iter)
        PHASE(0, 0, 0, VMNOP, { STAGE(&As[1][0], A + a0 + ck); STAGE(&As[1][8192], A + a1 + ck); });
        PHASE(0, 0, 1, VMNOP, { STAGE(&Bs[1][0], Bt + b0 + ck); STAGE(&Bs[1][8192], Bt + b1 + ck); });
        PHASE(0, 1, 0, VMNOP, NOSTAGE);
        PHASE(0, 1, 1, VM0,   NOSTAGE);   // buf1 ready; >=2 phases after last issue
        // phases 5-8: read buf1 (tile 2i+1); stage buf0 (freed at phase-4 barrier)
        PHASE(1, 0, 0, VMNOP, { if (more) { STAGE(&As[0][0], A + a0 + cn); STAGE(&As[0][8192], A + a1 + cn); } });
        PHASE(1, 0, 1, VMNOP, { if (more) { STAGE(&Bs[0][0], Bt + b0 + cn); STAGE(&Bs[0][8192], Bt + b1 + cn); } });
        PHASE(1, 1, 0, VMNOP, NOSTAGE);
        PHASE(1, 1, 1, VM0,   NOSTAGE);   // buf0 ready for next iter (no-op on last)
    }

    // epilogue: row = m0+wr+f*16+lr, cols = n0+wc+g*16+lk*4 + (0..3)
#pragma unroll
    for (int f = 0; f < 8; ++f) {
        const int row = m0 + wr + f * 16 + lr;
#pragma unroll
        for (int g = 0; g < 4; ++g) {
            const int col = n0 + wc + g * 16 + lk * 4;
            const float4 bv = *(const float4*)&bias[col];
            float v0 = acc[f][g][0] + bv.x;
            float v1 = acc[f][g][1] + bv.y;
            float v2 = acc[f][g][2] + bv.z;
            float v3 = acc[f][g][3] + bv.w;
            if (QKV) {
                if (col < 512) {   // q pre-scale (uniform per 4-col block)
                    v0 *= 0.17677669529663689f; v1 *= 0.17677669529663689f;
                    v2 *= 0.17677669529663689f; v3 *= 0.17677669529663689f;
                }
                ushort4v o;
                o.x = f2bf(v0); o.y = f2bf(v1); o.z = f2bf(v2); o.w = f2bf(v3);
                *(ushort4v*)&((ushort_t*)out)[(size_t)row * NSTR + col] = o;
            } else {
                float4 o; o.x = v0; o.y = v1; o.z = v2; o.w = v3;
                *(float4*)&((float*)out)[(size_t)row * NSTR + col] = o;
            }
        }
    }
}

// ---------- fused window attention: one wave per (b,h) ----------
// qkv: [100352][1536] bf16 (q pre-scaled, bias added). cm: [64][16][64][64] f32.
// out: [100352][512] bf16  (out[b*49+n][h*32+d])
#define PL_STRIDE 80   // bf16 elems; 160B rows -> 16B aligned
#define VT_STRIDE 88   // bf16 elems; 176B rows -> 16B aligned, low bank conflict
__global__ __launch_bounds__(256, 2)
void attn_kernel(const ushort_t* __restrict__ qkv, const float* __restrict__ cm,
                 ushort_t* __restrict__ out)
{
    // Pl region (40960B) is unioned with the cm tile (16640B); vT separate (22528B).
    __shared__ alignas(16) char smem[4 * 64 * PL_STRIDE * 2 + 4 * 32 * VT_STRIDE * 2];
    float* cmf = (float*)smem;                                    // [64][65]
    ushort_t* Pl = (ushort_t*)smem;                               // [4][64][PL_STRIDE]
    ushort_t* vT = (ushort_t*)(smem + 4 * 64 * PL_STRIDE * 2);    // [4][32][VT_STRIDE]

    const int w = blockIdx.x, h = blockIdx.y, ig = blockIdx.z;    // r1 grid (w fastest)
    const int tid = threadIdx.x;
    const int wid = tid >> 6, lane = tid & 63;
    const int lr = lane & 15, lk = lane >> 4;
    const int b = (ig * 4 + wid) * 64 + w;       // b % 64 == w (mask window index)

    // stage cm[w][h] tile into LDS (shared by the 4 waves)
    const float* cmsrc = cm + ((size_t)(w * 16 + h) << 12);
    for (int t = tid; t < 4096; t += 256)
        cmf[(t >> 6) * 65 + (t & 63)] = cmsrc[t];
    __syncthreads();

    const size_t base = (size_t)b * 49 * 1536 + h * 32;

    // q/k fragments (rows padded 49->64 via clamp; garbage killed by cm = -30000)
    short8 aq[4], bk[4];
#pragma unroll
    for (int i = 0; i < 4; ++i) {
        int n = i * 16 + lr; n = n > 48 ? 48 : n;
        aq[i] = *(const short8*)&qkv[base + (size_t)n * 1536 + lk * 8];
    }
#pragma unroll
    for (int j = 0; j < 4; ++j) {
        int m = j * 16 + lr; m = m > 48 ? 48 : m;
        bk[j] = *(const short8*)&qkv[base + 512 + (size_t)m * 1536 + lk * 8];
    }

    f32x4 s[4][4];
#pragma unroll
    for (int i = 0; i < 4; ++i)
#pragma unroll
        for (int j = 0; j < 4; ++j)
#pragma unroll
            for (int r = 0; r < 4; ++r) s[i][j][r] = 0.f;
#pragma unroll
    for (int i = 0; i < 4; ++i)
#pragma unroll
        for (int j = 0; j < 4; ++j)
            s[i][j] = __builtin_amdgcn_mfma_f32_16x16x32_bf16(aq[i], bk[j], s[i][j], 0, 0, 0);

    // v load (row m = lane) and transposed LDS store vT[d][m]
    short8 vv[4];
#pragma unroll
    for (int t = 0; t < 4; ++t)
#pragma unroll
        for (int e = 0; e < 8; ++e) vv[t][e] = 0;
    if (lane < 49) {
        const ushort_t* vp = &qkv[base + 1024 + (size_t)lane * 1536];
#pragma unroll
        for (int t = 0; t < 4; ++t) vv[t] = *(const short8*)(vp + t * 8);
    }
    ushort_t* vTw = vT + wid * 32 * VT_STRIDE;
#pragma unroll
    for (int t = 0; t < 4; ++t)
#pragma unroll
        for (int e = 0; e < 8; ++e)
            vTw[(t * 8 + e) * VT_STRIDE + lane] = (ushort_t)vv[t][e];

    // add bias+mask, wave-parallel softmax (rows are (lk*4+r)+16i, cols lane-spread)
#pragma unroll
    for (int i = 0; i < 4; ++i) {
#pragma unroll
        for (int r = 0; r < 4; ++r) {
            const int row = i * 16 + lk * 4 + r;
            float v0 = s[i][0][r] + cmf[row * 65 + lr];
            float v1 = s[i][1][r] + cmf[row * 65 + 16 + lr];
            float v2 = s[i][2][r] + cmf[row * 65 + 32 + lr];
            float v3 = s[i][3][r] + cmf[row * 65 + 48 + lr];
            float mx = fmaxf(fmaxf(v0, v1), fmaxf(v2, v3));
#pragma unroll
            for (int t = 1; t < 16; t <<= 1) mx = fmaxf(mx, __shfl_xor(mx, t, 64));
            v0 = __expf(v0 - mx); v1 = __expf(v1 - mx);
            v2 = __expf(v2 - mx); v3 = __expf(v3 - mx);
            float sm = v0 + v1 + v2 + v3;
#pragma unroll
            for (int t = 1; t < 16; t <<= 1) sm += __shfl_xor(sm, t, 64);
            const float inv = 1.0f / sm;
            s[i][0][r] = v0 * inv; s[i][1][r] = v1 * inv;
            s[i][2][r] = v2 * inv; s[i][3][r] = v3 * inv;
        }
    }
    __syncthreads();   // all waves done reading cm tile; safe to overwrite with P

    // P -> bf16 -> LDS (per-wave slice)
    ushort_t* Pw = Pl + wid * 64 * PL_STRIDE;
#pragma unroll
    for (int i = 0; i < 4; ++i)
#pragma unroll
        for (int j = 0; j < 4; ++j)
#pragma unroll
            for (int r = 0; r < 4; ++r)
                Pw[(i * 16 + lk * 4 + r) * PL_STRIDE + j * 16 + lr] = f2bf(s[i][j][r]);

    // PV: out[n][d] = sum_m P[n][m] * v[m][d]; operands swapped so each lane
    // holds 4 consecutive d for one n -> packed 8B stores.
    f32x4 o[4][2];
#pragma unroll
    for (int i = 0; i < 4; ++i)
#pragma unroll
        for (int jb = 0; jb < 2; ++jb)
#pragma unroll
            for (int r = 0; r < 4; ++r) o[i][jb][r] = 0.f;
#pragma unroll
    for (int ks = 0; ks < 2; ++ks) {
        short8 pa[4], vb[2];
#pragma unroll
        for (int i = 0; i < 4; ++i)
            pa[i] = *(const short8*)&Pw[(i * 16 + lr) * PL_STRIDE + ks * 32 + lk * 8];
#pragma unroll
        for (int jb = 0; jb < 2; ++jb)
            vb[jb] = *(const short8*)&vTw[(jb * 16 + lr) * VT_STRIDE + ks * 32 + lk * 8];
#pragma unroll
        for (int i = 0; i < 4; ++i)
#pragma unroll
            for (int jb = 0; jb < 2; ++jb)
                o[i][jb] = __builtin_amdgcn_mfma_f32_16x16x32_bf16(vb[jb], pa[i], o[i][jb], 0, 0, 0);
    }

    // write attn output (bf16) as [b*49+n][h*32+d]; n = i*16+lr, d = jb*16+lk*4+(0..3)
    const size_t obase = (size_t)b * 49 * 512 + h * 32;
#pragma unroll
    for (int i = 0; i < 4; ++i) {
        const int n = i * 16 + lr;
        if (n < 49) {
#pragma unroll
            for (int jb = 0; jb < 2; ++jb) {
                ushort4v ov;
                ov.x = f2bf(o[i][jb][0]); ov.y = f2bf(o[i][jb][1]);
                ov.z = f2bf(o[i][jb][2]); ov.w = f2bf(o[i][jb][3]);
                *(ushort4v*)&out[obase + (size_t)n * 512 + jb * 16 + lk * 4] = ov;
            }
        }
    }
}

// ---------- launch ----------
extern "C" void kernel_launch(void* const* d_in, const int* in_sizes, int n_in,
                              void* d_out, int out_size, void* d_ws, size_t ws_size,
                              hipStream_t stream)
{
    const float* x         = (const float*)d_in[0];
    const float* mask      = (const float*)d_in[1];
    const float* qkv_w     = (const float*)d_in[2];
    const float* qkv_b     = (const float*)d_in[3];
    const float* proj_w    = (const float*)d_in[4];
    const float* proj_b    = (const float*)d_in[5];
    const float* rel_table = (const float*)d_in[6];
    const int*   rel_index = (const int*)d_in[7];

    char* ws = (char*)d_ws;
    ushort_t* xb  = (ushort_t*)ws;                      // x bf16 / attn-out reuse: 102,760,448 B
    ushort_t* qkv = (ushort_t*)(ws + 102760448);        // 308,281,344 B
    ushort_t* wtq = (ushort_t*)(ws + 411041792);        // 1,572,864 B
    ushort_t* wtp = (ushort_t*)(ws + 412614656);        // 524,288 B
    float*    cm  = (float*)  (ws + 413138944);         // 16,777,216 B (total ~430 MB)

    conv_x_kernel<<<50176, 256, 0, stream>>>(x, xb);
    prep_weights<<<3072, 256, 0, stream>>>(qkv_w, proj_w, wtq, wtp);
    build_cm<<<16384, 256, 0, stream>>>(mask, rel_table, rel_index, cm);

    // QKV GEMM: [100352,512] x [512,1536] -> qkv bf16 (q pre-scaled); 392x6 tiles
    gemm8<6, 1536, true, 512><<<2352, 512, 0, stream>>>(xb, wtq, qkv_b, qkv);

    // attention: grid (window fast, head, image-group), 4 waves/block
    attn_kernel<<<dim3(64, 16, 8), 256, 0, stream>>>(qkv, cm, xb);

    // proj GEMM: [100352,512] x [512,512] -> d_out f32; 392x2 tiles
    gemm8<2, 512, false, 512><<<784, 512, 0, stream>>>(xb, wtp, proj_b, d_out);
}

// Round 5
// 656.581 us; speedup vs baseline: 1.0661x; 1.0661x over previous
//
#include <hip/hip_runtime.h>

typedef unsigned short ushort_t;
typedef short short8 __attribute__((ext_vector_type(8)));
typedef float f32x4 __attribute__((ext_vector_type(4)));
typedef unsigned short ushort4v __attribute__((ext_vector_type(4)));

// ---------- helpers ----------
__device__ __forceinline__ ushort_t f2bf(float f) {
    unsigned int u = __float_as_uint(f);
    u = (u + 0x7fffu + ((u >> 16) & 1u)) >> 16;
    return (ushort_t)u;
}

__device__ __forceinline__ void async16(void* lds, const void* g) {
    __builtin_amdgcn_global_load_lds(
        (const __attribute__((address_space(1))) unsigned int*)g,
        (__attribute__((address_space(3))) unsigned int*)lds, 16, 0, 0);
}

// ---------- prep kernels ----------
__global__ void conv_x_kernel(const float* __restrict__ in, ushort_t* __restrict__ out) {
    int i = blockIdx.x * 256 + threadIdx.x;      // grid sized exactly: 50176*256 = 12845056
    float4 v = ((const float4*)in)[i];
    ushort4v o;
    o.x = f2bf(v.x); o.y = f2bf(v.y); o.z = f2bf(v.z); o.w = f2bf(v.w);
    ((ushort4v*)out)[i] = o;
}

__global__ void prep_weights(const float* __restrict__ qkv_w, const float* __restrict__ proj_w,
                             ushort_t* __restrict__ wtq, ushort_t* __restrict__ wtp) {
    int o = blockIdx.x * 256 + threadIdx.x;      // grid 3072*256 = 786432
    if (o < 1536 * 512) {
        int n = o >> 9, k = o & 511;
        wtq[o] = f2bf(qkv_w[k * 1536 + n]);      // wtq[n][k] = W[k][n]
    }
    if (o < 512 * 512) {
        int n = o >> 9, k = o & 511;
        wtp[o] = f2bf(proj_w[k * 512 + n]);
    }
}

__global__ void build_cm(const float* __restrict__ mask, const float* __restrict__ rel_table,
                         const int* __restrict__ rel_index, float* __restrict__ cm) {
    int o = blockIdx.x * 256 + threadIdx.x;      // grid 16384*256 = 4194304 = 64*16*64*64
    int c = o & 63, r = (o >> 6) & 63, h = (o >> 12) & 15, w = o >> 16;
    float v = -30000.0f;
    if (r < 49 && c < 49)
        v = rel_table[rel_index[r * 49 + c] * 16 + h] + mask[w * 2401 + r * 49 + c];
    cm[o] = v;
}

// ---------- 256x256 8-phase bf16 MFMA GEMM ----------
// C[M][N] = A[M][K] * Bt[N][K]^T + bias. BM=BN=256, BK=64, 8 waves (2M x 4N),
// double-buffered LDS (128 KiB, 1 block/CU). Race-free stage schedule (r4).
// LDS swizzle (r5 fix): rows are 128 B = exactly 32 banks, so only the chunk
// index carries bank info. XOR the 16B-chunk index with the FULL (row&7):
// per ds_read_b128, p = (ks*4+lk) ^ (lr&7) puts exactly 8 lanes on each of
// the 8 chunks -> every bank gets exactly 8 accesses = b128 floor, no
// conflicts. Applied on the GLOBAL source and the ds_read address (rule 21).

#define STAGE(ldsbase, gbase) do {                                              \
    _Pragma("unroll")                                                           \
    for (int j_ = 0; j_ < 2; ++j_) {                                            \
        const int idx_ = j_ * 512 + tid;                                        \
        const int row_ = idx_ >> 3;                                             \
        const int sc_  = (((idx_ & 7) ^ (row_ & 7)) << 3);                      \
        async16((char*)(ldsbase) + idx_ * 16, (gbase) + (size_t)row_ * K + sc_);\
    }                                                                           \
} while (0)

#define VMNOP ((void)0)
#define VM0 asm volatile("s_waitcnt vmcnt(0)" ::: "memory")
#define NOSTAGE ((void)0)

#define PHASE(buf, mh, nh, WAITST, ...) do {                                    \
    short8 af_[4][2], bf_[2][2];                                                \
    _Pragma("unroll")                                                           \
    for (int f_ = 0; f_ < 4; ++f_) {                                            \
        const int ar_ = wr + ((mh) * 4 + f_) * 16 + lr;                         \
        _Pragma("unroll")                                                       \
        for (int ks_ = 0; ks_ < 2; ++ks_)                                       \
            af_[f_][ks_] = *(const short8*)&As[buf][ar_ * 64 + ((ks_ * 32 + lk * 8) ^ ((ar_ & 7) << 3))]; \
    }                                                                           \
    _Pragma("unroll")                                                           \
    for (int g_ = 0; g_ < 2; ++g_) {                                            \
        const int br_ = wc + ((nh) * 2 + g_) * 16 + lr;                         \
        _Pragma("unroll")                                                       \
        for (int ks_ = 0; ks_ < 2; ++ks_)                                       \
            bf_[g_][ks_] = *(const short8*)&Bs[buf][br_ * 64 + ((ks_ * 32 + lk * 8) ^ ((br_ & 7) << 3))]; \
    }                                                                           \
    __VA_ARGS__;                                                                \
    __builtin_amdgcn_s_barrier();                                               \
    asm volatile("s_waitcnt lgkmcnt(0)" ::: "memory");                          \
    __builtin_amdgcn_sched_barrier(0);                                          \
    __builtin_amdgcn_s_setprio(1);                                              \
    _Pragma("unroll")                                                           \
    for (int f_ = 0; f_ < 4; ++f_)                                              \
        _Pragma("unroll")                                                       \
        for (int g_ = 0; g_ < 2; ++g_)                                          \
            _Pragma("unroll")                                                   \
            for (int ks_ = 0; ks_ < 2; ++ks_)                                   \
                acc[(mh) * 4 + f_][(nh) * 2 + g_] = __builtin_amdgcn_mfma_f32_16x16x32_bf16( \
                    bf_[g_][ks_], af_[f_][ks_], acc[(mh) * 4 + f_][(nh) * 2 + g_], 0, 0, 0); \
    __builtin_amdgcn_s_setprio(0);                                              \
    WAITST;                                                                     \
    __builtin_amdgcn_s_barrier();                                               \
} while (0)

template<int NB_N, int NSTR, bool QKV, int K>
__global__ __launch_bounds__(512, 2)
void gemm8(const ushort_t* __restrict__ A, const ushort_t* __restrict__ Bt,
           const float* __restrict__ bias, void* __restrict__ out)
{
    __shared__ alignas(16) ushort_t As[2][256 * 64];   // 64 KiB
    __shared__ alignas(16) ushort_t Bs[2][256 * 64];   // 64 KiB

    const int tid = threadIdx.x;
    const int wid = tid >> 6, lane = tid & 63;
    const int lr = lane & 15, lk = lane >> 4;
    const int wr = (wid >> 2) * 128;     // 0 / 128
    const int wc = (wid & 3) * 64;       // 0..192

    // XCD-aware bijective swizzle (grid % 8 == 0 for both GEMMs)
    const int chunk = gridDim.x >> 3;
    const int wg = ((int)blockIdx.x & 7) * chunk + ((int)blockIdx.x >> 3);
    const int nb = wg % NB_N;
    const int mb = wg / NB_N;
    const int m0 = mb << 8, n0 = nb << 8;

    const size_t a0 = (size_t)m0 * K;
    const size_t a1 = (size_t)(m0 + 128) * K;
    const size_t b0 = (size_t)n0 * K;
    const size_t b1 = (size_t)(n0 + 128) * K;

    f32x4 acc[8][4];
#pragma unroll
    for (int f = 0; f < 8; ++f)
#pragma unroll
        for (int g = 0; g < 4; ++g)
#pragma unroll
            for (int r = 0; r < 4; ++r) acc[f][g][r] = 0.f;

    // prologue: tile0 -> buf0, drain, barrier
    STAGE(&As[0][0],    A  + a0);
    STAGE(&As[0][8192], A  + a1);
    STAGE(&Bs[0][0],    Bt + b0);
    STAGE(&Bs[0][8192], Bt + b1);
    VM0;
    __builtin_amdgcn_s_barrier();

    const int NI = K >> 7;   // tile pairs; NI=4 for K=512
    for (int i = 0; i < NI; ++i) {
        const int ck = (2 * i + 1) << 6;   // K-offset of tile for buf1 (read this iter, ph 5-8)
        const int cn = (2 * i + 2) << 6;   // K-offset of tile for buf0 (read next iter)
        const bool more = (i < NI - 1);
        // phases 1-4: read buf0 (tile 2i); stage buf1 (freed at end of prev iter)
        PHASE(0, 0, 0, VMNOP, { STAGE(&As[1][0], A + a0 + ck); STAGE(&As[1][8192], A + a1 + ck); });
        PHASE(0, 0, 1, VMNOP, { STAGE(&Bs[1][0], Bt + b0 + ck); STAGE(&Bs[1][8192], Bt + b1 + ck); });
        PHASE(0, 1, 0, VMNOP, NOSTAGE);
        PHASE(0, 1, 1, VM0,   NOSTAGE);   // buf1 ready; >=2 phases after last issue
        // phases 5-8: read buf1 (tile 2i+1); stage buf0 (freed at phase-4 barrier)
        PHASE(1, 0, 0, VMNOP, { if (more) { STAGE(&As[0][0], A + a0 + cn); STAGE(&As[0][8192], A + a1 + cn); } });
        PHASE(1, 0, 1, VMNOP, { if (more) { STAGE(&Bs[0][0], Bt + b0 + cn); STAGE(&Bs[0][8192], Bt + b1 + cn); } });
        PHASE(1, 1, 0, VMNOP, NOSTAGE);
        PHASE(1, 1, 1, VM0,   NOSTAGE);   // buf0 ready for next iter (no-op on last)
    }

    // epilogue: row = m0+wr+f*16+lr, cols = n0+wc+g*16+lk*4 + (0..3)
#pragma unroll
    for (int f = 0; f < 8; ++f) {
        const int row = m0 + wr + f * 16 + lr;
#pragma unroll
        for (int g = 0; g < 4; ++g) {
            const int col = n0 + wc + g * 16 + lk * 4;
            const float4 bv = *(const float4*)&bias[col];
            float v0 = acc[f][g][0] + bv.x;
            float v1 = acc[f][g][1] + bv.y;
            float v2 = acc[f][g][2] + bv.z;
            float v3 = acc[f][g][3] + bv.w;
            if (QKV) {
                if (col < 512) {   // q pre-scale (uniform per 4-col block)
                    v0 *= 0.17677669529663689f; v1 *= 0.17677669529663689f;
                    v2 *= 0.17677669529663689f; v3 *= 0.17677669529663689f;
                }
                ushort4v o;
                o.x = f2bf(v0); o.y = f2bf(v1); o.z = f2bf(v2); o.w = f2bf(v3);
                *(ushort4v*)&((ushort_t*)out)[(size_t)row * NSTR + col] = o;
            } else {
                float4 o; o.x = v0; o.y = v1; o.z = v2; o.w = v3;
                *(float4*)&((float*)out)[(size_t)row * NSTR + col] = o;
            }
        }
    }
}

// ---------- fused window attention: one wave per (b,h) ----------
// qkv: [100352][1536] bf16 (q pre-scaled, bias added). cm: [64][16][64][64] f32.
// out: [100352][512] bf16  (out[b*49+n][h*32+d])
#define PL_STRIDE 80   // bf16 elems; 160B rows -> 16B aligned
#define VT_STRIDE 88   // bf16 elems; 176B rows -> 16B aligned, low bank conflict
__global__ __launch_bounds__(256, 2)
void attn_kernel(const ushort_t* __restrict__ qkv, const float* __restrict__ cm,
                 ushort_t* __restrict__ out)
{
    // Pl region (40960B) is unioned with the cm tile (16640B); vT separate (22528B).
    __shared__ alignas(16) char smem[4 * 64 * PL_STRIDE * 2 + 4 * 32 * VT_STRIDE * 2];
    float* cmf = (float*)smem;                                    // [64][65]
    ushort_t* Pl = (ushort_t*)smem;                               // [4][64][PL_STRIDE]
    ushort_t* vT = (ushort_t*)(smem + 4 * 64 * PL_STRIDE * 2);    // [4][32][VT_STRIDE]

    const int w = blockIdx.x, h = blockIdx.y, ig = blockIdx.z;    // r1 grid (w fastest)
    const int tid = threadIdx.x;
    const int wid = tid >> 6, lane = tid & 63;
    const int lr = lane & 15, lk = lane >> 4;
    const int b = (ig * 4 + wid) * 64 + w;       // b % 64 == w (mask window index)

    // stage cm[w][h] tile into LDS (shared by the 4 waves)
    const float* cmsrc = cm + ((size_t)(w * 16 + h) << 12);
    for (int t = tid; t < 4096; t += 256)
        cmf[(t >> 6) * 65 + (t & 63)] = cmsrc[t];
    __syncthreads();

    const size_t base = (size_t)b * 49 * 1536 + h * 32;

    // q/k fragments (rows padded 49->64 via clamp; garbage killed by cm = -30000)
    short8 aq[4], bk[4];
#pragma unroll
    for (int i = 0; i < 4; ++i) {
        int n = i * 16 + lr; n = n > 48 ? 48 : n;
        aq[i] = *(const short8*)&qkv[base + (size_t)n * 1536 + lk * 8];
    }
#pragma unroll
    for (int j = 0; j < 4; ++j) {
        int m = j * 16 + lr; m = m > 48 ? 48 : m;
        bk[j] = *(const short8*)&qkv[base + 512 + (size_t)m * 1536 + lk * 8];
    }

    f32x4 s[4][4];
#pragma unroll
    for (int i = 0; i < 4; ++i)
#pragma unroll
        for (int j = 0; j < 4; ++j)
#pragma unroll
            for (int r = 0; r < 4; ++r) s[i][j][r] = 0.f;
#pragma unroll
    for (int i = 0; i < 4; ++i)
#pragma unroll
        for (int j = 0; j < 4; ++j)
            s[i][j] = __builtin_amdgcn_mfma_f32_16x16x32_bf16(aq[i], bk[j], s[i][j], 0, 0, 0);

    // v load (row m = lane) and transposed LDS store vT[d][m]
    short8 vv[4];
#pragma unroll
    for (int t = 0; t < 4; ++t)
#pragma unroll
        for (int e = 0; e < 8; ++e) vv[t][e] = 0;
    if (lane < 49) {
        const ushort_t* vp = &qkv[base + 1024 + (size_t)lane * 1536];
#pragma unroll
        for (int t = 0; t < 4; ++t) vv[t] = *(const short8*)(vp + t * 8);
    }
    ushort_t* vTw = vT + wid * 32 * VT_STRIDE;
#pragma unroll
    for (int t = 0; t < 4; ++t)
#pragma unroll
        for (int e = 0; e < 8; ++e)
            vTw[(t * 8 + e) * VT_STRIDE + lane] = (ushort_t)vv[t][e];

    // add bias+mask, wave-parallel softmax (rows are (lk*4+r)+16i, cols lane-spread)
#pragma unroll
    for (int i = 0; i < 4; ++i) {
#pragma unroll
        for (int r = 0; r < 4; ++r) {
            const int row = i * 16 + lk * 4 + r;
            float v0 = s[i][0][r] + cmf[row * 65 + lr];
            float v1 = s[i][1][r] + cmf[row * 65 + 16 + lr];
            float v2 = s[i][2][r] + cmf[row * 65 + 32 + lr];
            float v3 = s[i][3][r] + cmf[row * 65 + 48 + lr];
            float mx = fmaxf(fmaxf(v0, v1), fmaxf(v2, v3));
#pragma unroll
            for (int t = 1; t < 16; t <<= 1) mx = fmaxf(mx, __shfl_xor(mx, t, 64));
            v0 = __expf(v0 - mx); v1 = __expf(v1 - mx);
            v2 = __expf(v2 - mx); v3 = __expf(v3 - mx);
            float sm = v0 + v1 + v2 + v3;
#pragma unroll
            for (int t = 1; t < 16; t <<= 1) sm += __shfl_xor(sm, t, 64);
            const float inv = 1.0f / sm;
            s[i][0][r] = v0 * inv; s[i][1][r] = v1 * inv;
            s[i][2][r] = v2 * inv; s[i][3][r] = v3 * inv;
        }
    }
    __syncthreads();   // all waves done reading cm tile; safe to overwrite with P

    // P -> bf16 -> LDS (per-wave slice)
    ushort_t* Pw = Pl + wid * 64 * PL_STRIDE;
#pragma unroll
    for (int i = 0; i < 4; ++i)
#pragma unroll
        for (int j = 0; j < 4; ++j)
#pragma unroll
            for (int r = 0; r < 4; ++r)
                Pw[(i * 16 + lk * 4 + r) * PL_STRIDE + j * 16 + lr] = f2bf(s[i][j][r]);

    // PV: out[n][d] = sum_m P[n][m] * v[m][d]; operands swapped so each lane
    // holds 4 consecutive d for one n -> packed 8B stores.
    f32x4 o[4][2];
#pragma unroll
    for (int i = 0; i < 4; ++i)
#pragma unroll
        for (int jb = 0; jb < 2; ++jb)
#pragma unroll
            for (int r = 0; r < 4; ++r) o[i][jb][r] = 0.f;
#pragma unroll
    for (int ks = 0; ks < 2; ++ks) {
        short8 pa[4], vb[2];
#pragma unroll
        for (int i = 0; i < 4; ++i)
            pa[i] = *(const short8*)&Pw[(i * 16 + lr) * PL_STRIDE + ks * 32 + lk * 8];
#pragma unroll
        for (int jb = 0; jb < 2; ++jb)
            vb[jb] = *(const short8*)&vTw[(jb * 16 + lr) * VT_STRIDE + ks * 32 + lk * 8];
#pragma unroll
        for (int i = 0; i < 4; ++i)
#pragma unroll
            for (int jb = 0; jb < 2; ++jb)
                o[i][jb] = __builtin_amdgcn_mfma_f32_16x16x32_bf16(vb[jb], pa[i], o[i][jb], 0, 0, 0);
    }

    // write attn output (bf16) as [b*49+n][h*32+d]; n = i*16+lr, d = jb*16+lk*4+(0..3)
    const size_t obase = (size_t)b * 49 * 512 + h * 32;
#pragma unroll
    for (int i = 0; i < 4; ++i) {
        const int n = i * 16 + lr;
        if (n < 49) {
#pragma unroll
            for (int jb = 0; jb < 2; ++jb) {
                ushort4v ov;
                ov.x = f2bf(o[i][jb][0]); ov.y = f2bf(o[i][jb][1]);
                ov.z = f2bf(o[i][jb][2]); ov.w = f2bf(o[i][jb][3]);
                *(ushort4v*)&out[obase + (size_t)n * 512 + jb * 16 + lk * 4] = ov;
            }
        }
    }
}

// ---------- launch ----------
extern "C" void kernel_launch(void* const* d_in, const int* in_sizes, int n_in,
                              void* d_out, int out_size, void* d_ws, size_t ws_size,
                              hipStream_t stream)
{
    const float* x         = (const float*)d_in[0];
    const float* mask      = (const float*)d_in[1];
    const float* qkv_w     = (const float*)d_in[2];
    const float* qkv_b     = (const float*)d_in[3];
    const float* proj_w    = (const float*)d_in[4];
    const float* proj_b    = (const float*)d_in[5];
    const float* rel_table = (const float*)d_in[6];
    const int*   rel_index = (const int*)d_in[7];

    char* ws = (char*)d_ws;
    ushort_t* xb  = (ushort_t*)ws;                      // x bf16 / attn-out reuse: 102,760,448 B
    ushort_t* qkv = (ushort_t*)(ws + 102760448);        // 308,281,344 B
    ushort_t* wtq = (ushort_t*)(ws + 411041792);        // 1,572,864 B
    ushort_t* wtp = (ushort_t*)(ws + 412614656);        // 524,288 B
    float*    cm  = (float*)  (ws + 413138944);         // 16,777,216 B (total ~430 MB)

    conv_x_kernel<<<50176, 256, 0, stream>>>(x, xb);
    prep_weights<<<3072, 256, 0, stream>>>(qkv_w, proj_w, wtq, wtp);
    build_cm<<<16384, 256, 0, stream>>>(mask, rel_table, rel_index, cm);

    // QKV GEMM: [100352,512] x [512,1536] -> qkv bf16 (q pre-scaled); 392x6 tiles
    gemm8<6, 1536, true, 512><<<2352, 512, 0, stream>>>(xb, wtq, qkv_b, qkv);

    // attention: grid (window fast, head, image-group), 4 waves/block
    attn_kernel<<<dim3(64, 16, 8), 256, 0, stream>>>(qkv, cm, xb);

    // proj GEMM: [100352,512] x [512,512] -> d_out f32; 392x2 tiles
    gemm8<2, 512, false, 512><<<784, 512, 0, stream>>>(xb, wtp, proj_b, d_out);
}

// Round 6
// 643.916 us; speedup vs baseline: 1.0871x; 1.0197x over previous
//
#include <hip/hip_runtime.h>

typedef unsigned short ushort_t;
typedef short short8 __attribute__((ext_vector_type(8)));
typedef float f32x4 __attribute__((ext_vector_type(4)));
typedef unsigned short ushort4v __attribute__((ext_vector_type(4)));

// ---------- helpers ----------
__device__ __forceinline__ ushort_t f2bf(float f) {
    unsigned int u = __float_as_uint(f);
    u = (u + 0x7fffu + ((u >> 16) & 1u)) >> 16;
    return (ushort_t)u;
}

__device__ __forceinline__ void async16(void* lds, const void* g) {
    __builtin_amdgcn_global_load_lds(
        (const __attribute__((address_space(1))) unsigned int*)g,
        (__attribute__((address_space(3))) unsigned int*)lds, 16, 0, 0);
}

// ---------- prep kernels ----------
__global__ void conv_x_kernel(const float* __restrict__ in, ushort_t* __restrict__ out) {
    int i = blockIdx.x * 256 + threadIdx.x;      // grid sized exactly: 50176*256 = 12845056
    float4 v = ((const float4*)in)[i];
    ushort4v o;
    o.x = f2bf(v.x); o.y = f2bf(v.y); o.z = f2bf(v.z); o.w = f2bf(v.w);
    ((ushort4v*)out)[i] = o;
}

__global__ void prep_weights(const float* __restrict__ qkv_w, const float* __restrict__ proj_w,
                             ushort_t* __restrict__ wtq, ushort_t* __restrict__ wtp) {
    int o = blockIdx.x * 256 + threadIdx.x;      // grid 3072*256 = 786432
    if (o < 1536 * 512) {
        int n = o >> 9, k = o & 511;
        wtq[o] = f2bf(qkv_w[k * 1536 + n]);      // wtq[n][k] = W[k][n]
    }
    if (o < 512 * 512) {
        int n = o >> 9, k = o & 511;
        wtp[o] = f2bf(proj_w[k * 512 + n]);
    }
}

__global__ void build_cm(const float* __restrict__ mask, const float* __restrict__ rel_table,
                         const int* __restrict__ rel_index, float* __restrict__ cm) {
    int o = blockIdx.x * 256 + threadIdx.x;      // grid 16384*256 = 4194304 = 64*16*64*64
    int c = o & 63, r = (o >> 6) & 63, h = (o >> 12) & 15, w = o >> 16;
    float v = -30000.0f;
    if (r < 49 && c < 49)
        v = rel_table[rel_index[r * 49 + c] * 16 + h] + mask[w * 2401 + r * 49 + c];
    cm[o] = v;
}

// ---------- 256x256 bf16 MFMA GEMM, 2 phases/K-tile with operand reuse ----------
// C[M][N] = A[M][K] * Bt[N][K]^T + bias. BM=BN=256, BK=64, 8 waves (2M x 4N),
// double-buffered LDS (128 KiB, 1 block/CU).
// r6 fix (LDS-read-volume bound at r5): hold bf[4][2] in registers for the
// whole K-tile and af[4][2] per M-half -> 24 ds_read_b128 per wave per K-tile
// (the A+B data floor) instead of 48. Phase A: load bf + af(mh=0), stage next
// tile into the other buffer, 32 MFMA. Phase B: load af(mh=1) only (issued
// into phase A's MFMA shadow), 32 MFMA, vmcnt(0) (~400 cyc after issue), bar.
// LDS swizzle: 16B-chunk index XOR (row&7), both sides (r5-verified, 0 confl).

#define STAGE(ldsbase, gbase) do {                                              \
    _Pragma("unroll")                                                           \
    for (int j_ = 0; j_ < 2; ++j_) {                                            \
        const int idx_ = j_ * 512 + tid;                                        \
        const int row_ = idx_ >> 3;                                             \
        const int sc_  = (((idx_ & 7) ^ (row_ & 7)) << 3);                      \
        async16((char*)(ldsbase) + idx_ * 16, (gbase) + (size_t)row_ * K + sc_);\
    }                                                                           \
} while (0)

#define VM0 asm volatile("s_waitcnt vmcnt(0)" ::: "memory")

#define LOADA(buf, mh) do {                                                     \
    _Pragma("unroll")                                                           \
    for (int f_ = 0; f_ < 4; ++f_) {                                            \
        const int ar_ = wr + ((mh) * 4 + f_) * 16 + lr;                         \
        _Pragma("unroll")                                                       \
        for (int ks_ = 0; ks_ < 2; ++ks_)                                       \
            af[f_][ks_] = *(const short8*)&As[buf][ar_ * 64 + ((ks_ * 32 + lk * 8) ^ ((ar_ & 7) << 3))]; \
    }                                                                           \
} while (0)

#define LOADB(buf) do {                                                         \
    _Pragma("unroll")                                                           \
    for (int g_ = 0; g_ < 4; ++g_) {                                            \
        const int br_ = wc + g_ * 16 + lr;                                      \
        _Pragma("unroll")                                                       \
        for (int ks_ = 0; ks_ < 2; ++ks_)                                       \
            bf[g_][ks_] = *(const short8*)&Bs[buf][br_ * 64 + ((ks_ * 32 + lk * 8) ^ ((br_ & 7) << 3))]; \
    }                                                                           \
} while (0)

#define WAITLDS do {                                                            \
    __builtin_amdgcn_s_barrier();                                               \
    asm volatile("s_waitcnt lgkmcnt(0)" ::: "memory");                          \
    __builtin_amdgcn_sched_barrier(0);                                          \
} while (0)

#define MFMAH(mh) do {                                                          \
    __builtin_amdgcn_s_setprio(1);                                              \
    _Pragma("unroll")                                                           \
    for (int f_ = 0; f_ < 4; ++f_)                                              \
        _Pragma("unroll")                                                       \
        for (int g_ = 0; g_ < 4; ++g_)                                          \
            _Pragma("unroll")                                                   \
            for (int ks_ = 0; ks_ < 2; ++ks_)                                   \
                acc[(mh) * 4 + f_][g_] = __builtin_amdgcn_mfma_f32_16x16x32_bf16( \
                    bf[g_][ks_], af[f_][ks_], acc[(mh) * 4 + f_][g_], 0, 0, 0); \
    __builtin_amdgcn_s_setprio(0);                                              \
} while (0)

// One K-tile: phase A (16 reads + optional 8-gload stage + 32 MFMA),
// phase B (8 reads + 32 MFMA + vmcnt(0) + bar).
#define TILE(buf, DOSTAGE, koff) do {                                           \
    short8 af[4][2], bf[4][2];                                                  \
    LOADB(buf); LOADA(buf, 0);                                                  \
    if (DOSTAGE) {                                                              \
        STAGE(&As[(buf) ^ 1][0],    A  + a0 + (koff));                          \
        STAGE(&As[(buf) ^ 1][8192], A  + a1 + (koff));                          \
        STAGE(&Bs[(buf) ^ 1][0],    Bt + b0 + (koff));                          \
        STAGE(&Bs[(buf) ^ 1][8192], Bt + b1 + (koff));                          \
    }                                                                           \
    WAITLDS;                                                                    \
    MFMAH(0);                                                                   \
    LOADA(buf, 1);   /* issued into MFMA(0)'s shadow; same buf, no hazard */    \
    WAITLDS;                                                                    \
    MFMAH(1);                                                                   \
    VM0;             /* own-wave stages, issued ~2 MFMA clusters ago */         \
    __builtin_amdgcn_s_barrier();                                               \
} while (0)

template<int NB_N, int NSTR, bool QKV, int K>
__global__ __launch_bounds__(512, 2)
void gemm8(const ushort_t* __restrict__ A, const ushort_t* __restrict__ Bt,
           const float* __restrict__ bias, void* __restrict__ out)
{
    __shared__ alignas(16) ushort_t As[2][256 * 64];   // 64 KiB
    __shared__ alignas(16) ushort_t Bs[2][256 * 64];   // 64 KiB

    const int tid = threadIdx.x;
    const int wid = tid >> 6, lane = tid & 63;
    const int lr = lane & 15, lk = lane >> 4;
    const int wr = (wid >> 2) * 128;     // 0 / 128
    const int wc = (wid & 3) * 64;       // 0..192

    // XCD-aware bijective swizzle (grid % 8 == 0 for both GEMMs)
    const int chunk = gridDim.x >> 3;
    const int wg = ((int)blockIdx.x & 7) * chunk + ((int)blockIdx.x >> 3);
    const int nb = wg % NB_N;
    const int mb = wg / NB_N;
    const int m0 = mb << 8, n0 = nb << 8;

    const size_t a0 = (size_t)m0 * K;
    const size_t a1 = (size_t)(m0 + 128) * K;
    const size_t b0 = (size_t)n0 * K;
    const size_t b1 = (size_t)(n0 + 128) * K;

    f32x4 acc[8][4];
#pragma unroll
    for (int f = 0; f < 8; ++f)
#pragma unroll
        for (int g = 0; g < 4; ++g)
#pragma unroll
            for (int r = 0; r < 4; ++r) acc[f][g][r] = 0.f;

    // prologue: tile0 -> buf0, drain, barrier
    STAGE(&As[0][0],    A  + a0);
    STAGE(&As[0][8192], A  + a1);
    STAGE(&Bs[0][0],    Bt + b0);
    STAGE(&Bs[0][8192], Bt + b1);
    VM0;
    __builtin_amdgcn_s_barrier();

    const int KT = K >> 6;   // K-tiles; 8 for K=512
    for (int t = 0; t < KT; t += 2) {
        const int c1 = (t + 1) << 6;
        const int c2 = (t + 2) << 6;
        TILE(0, true,          c1);   // compute tile t   (buf0), stage t+1 -> buf1
        TILE(1, (t + 2 < KT),  c2);   // compute tile t+1 (buf1), stage t+2 -> buf0
    }

    // epilogue: row = m0+wr+f*16+lr, cols = n0+wc+g*16+lk*4 + (0..3)
#pragma unroll
    for (int f = 0; f < 8; ++f) {
        const int row = m0 + wr + f * 16 + lr;
#pragma unroll
        for (int g = 0; g < 4; ++g) {
            const int col = n0 + wc + g * 16 + lk * 4;
            const float4 bv = *(const float4*)&bias[col];
            float v0 = acc[f][g][0] + bv.x;
            float v1 = acc[f][g][1] + bv.y;
            float v2 = acc[f][g][2] + bv.z;
            float v3 = acc[f][g][3] + bv.w;
            if (QKV) {
                if (col < 512) {   // q pre-scale (uniform per 4-col block)
                    v0 *= 0.17677669529663689f; v1 *= 0.17677669529663689f;
                    v2 *= 0.17677669529663689f; v3 *= 0.17677669529663689f;
                }
                ushort4v o;
                o.x = f2bf(v0); o.y = f2bf(v1); o.z = f2bf(v2); o.w = f2bf(v3);
                *(ushort4v*)&((ushort_t*)out)[(size_t)row * NSTR + col] = o;
            } else {
                float4 o; o.x = v0; o.y = v1; o.z = v2; o.w = v3;
                *(float4*)&((float*)out)[(size_t)row * NSTR + col] = o;
            }
        }
    }
}

// ---------- fused window attention: one wave per (b,h) ----------
// qkv: [100352][1536] bf16 (q pre-scaled, bias added). cm: [64][16][64][64] f32.
// out: [100352][512] bf16  (out[b*49+n][h*32+d])
#define PL_STRIDE 80   // bf16 elems; 160B rows -> 16B aligned
#define VT_STRIDE 88   // bf16 elems; 176B rows -> 16B aligned, low bank conflict
__global__ __launch_bounds__(256, 2)
void attn_kernel(const ushort_t* __restrict__ qkv, const float* __restrict__ cm,
                 ushort_t* __restrict__ out)
{
    // Pl region (40960B) is unioned with the cm tile (16640B); vT separate (22528B).
    __shared__ alignas(16) char smem[4 * 64 * PL_STRIDE * 2 + 4 * 32 * VT_STRIDE * 2];
    float* cmf = (float*)smem;                                    // [64][65]
    ushort_t* Pl = (ushort_t*)smem;                               // [4][64][PL_STRIDE]
    ushort_t* vT = (ushort_t*)(smem + 4 * 64 * PL_STRIDE * 2);    // [4][32][VT_STRIDE]

    const int w = blockIdx.x, h = blockIdx.y, ig = blockIdx.z;    // r1 grid (w fastest)
    const int tid = threadIdx.x;
    const int wid = tid >> 6, lane = tid & 63;
    const int lr = lane & 15, lk = lane >> 4;
    const int b = (ig * 4 + wid) * 64 + w;       // b % 64 == w (mask window index)

    // stage cm[w][h] tile into LDS (shared by the 4 waves)
    const float* cmsrc = cm + ((size_t)(w * 16 + h) << 12);
    for (int t = tid; t < 4096; t += 256)
        cmf[(t >> 6) * 65 + (t & 63)] = cmsrc[t];
    __syncthreads();

    const size_t base = (size_t)b * 49 * 1536 + h * 32;

    // q/k fragments (rows padded 49->64 via clamp; garbage killed by cm = -30000)
    short8 aq[4], bk[4];
#pragma unroll
    for (int i = 0; i < 4; ++i) {
        int n = i * 16 + lr; n = n > 48 ? 48 : n;
        aq[i] = *(const short8*)&qkv[base + (size_t)n * 1536 + lk * 8];
    }
#pragma unroll
    for (int j = 0; j < 4; ++j) {
        int m = j * 16 + lr; m = m > 48 ? 48 : m;
        bk[j] = *(const short8*)&qkv[base + 512 + (size_t)m * 1536 + lk * 8];
    }

    f32x4 s[4][4];
#pragma unroll
    for (int i = 0; i < 4; ++i)
#pragma unroll
        for (int j = 0; j < 4; ++j)
#pragma unroll
            for (int r = 0; r < 4; ++r) s[i][j][r] = 0.f;
#pragma unroll
    for (int i = 0; i < 4; ++i)
#pragma unroll
        for (int j = 0; j < 4; ++j)
            s[i][j] = __builtin_amdgcn_mfma_f32_16x16x32_bf16(aq[i], bk[j], s[i][j], 0, 0, 0);

    // v load (row m = lane) and transposed LDS store vT[d][m]
    short8 vv[4];
#pragma unroll
    for (int t = 0; t < 4; ++t)
#pragma unroll
        for (int e = 0; e < 8; ++e) vv[t][e] = 0;
    if (lane < 49) {
        const ushort_t* vp = &qkv[base + 1024 + (size_t)lane * 1536];
#pragma unroll
        for (int t = 0; t < 4; ++t) vv[t] = *(const short8*)(vp + t * 8);
    }
    ushort_t* vTw = vT + wid * 32 * VT_STRIDE;
#pragma unroll
    for (int t = 0; t < 4; ++t)
#pragma unroll
        for (int e = 0; e < 8; ++e)
            vTw[(t * 8 + e) * VT_STRIDE + lane] = (ushort_t)vv[t][e];

    // add bias+mask, wave-parallel softmax (rows are (lk*4+r)+16i, cols lane-spread)
#pragma unroll
    for (int i = 0; i < 4; ++i) {
#pragma unroll
        for (int r = 0; r < 4; ++r) {
            const int row = i * 16 + lk * 4 + r;
            float v0 = s[i][0][r] + cmf[row * 65 + lr];
            float v1 = s[i][1][r] + cmf[row * 65 + 16 + lr];
            float v2 = s[i][2][r] + cmf[row * 65 + 32 + lr];
            float v3 = s[i][3][r] + cmf[row * 65 + 48 + lr];
            float mx = fmaxf(fmaxf(v0, v1), fmaxf(v2, v3));
#pragma unroll
            for (int t = 1; t < 16; t <<= 1) mx = fmaxf(mx, __shfl_xor(mx, t, 64));
            v0 = __expf(v0 - mx); v1 = __expf(v1 - mx);
            v2 = __expf(v2 - mx); v3 = __expf(v3 - mx);
            float sm = v0 + v1 + v2 + v3;
#pragma unroll
            for (int t = 1; t < 16; t <<= 1) sm += __shfl_xor(sm, t, 64);
            const float inv = 1.0f / sm;
            s[i][0][r] = v0 * inv; s[i][1][r] = v1 * inv;
            s[i][2][r] = v2 * inv; s[i][3][r] = v3 * inv;
        }
    }
    __syncthreads();   // all waves done reading cm tile; safe to overwrite with P

    // P -> bf16 -> LDS (per-wave slice)
    ushort_t* Pw = Pl + wid * 64 * PL_STRIDE;
#pragma unroll
    for (int i = 0; i < 4; ++i)
#pragma unroll
        for (int j = 0; j < 4; ++j)
#pragma unroll
            for (int r = 0; r < 4; ++r)
                Pw[(i * 16 + lk * 4 + r) * PL_STRIDE + j * 16 + lr] = f2bf(s[i][j][r]);

    // PV: out[n][d] = sum_m P[n][m] * v[m][d]; operands swapped so each lane
    // holds 4 consecutive d for one n -> packed 8B stores.
    f32x4 o[4][2];
#pragma unroll
    for (int i = 0; i < 4; ++i)
#pragma unroll
        for (int jb = 0; jb < 2; ++jb)
#pragma unroll
            for (int r = 0; r < 4; ++r) o[i][jb][r] = 0.f;
#pragma unroll
    for (int ks = 0; ks < 2; ++ks) {
        short8 pa[4], vb[2];
#pragma unroll
        for (int i = 0; i < 4; ++i)
            pa[i] = *(const short8*)&Pw[(i * 16 + lr) * PL_STRIDE + ks * 32 + lk * 8];
#pragma unroll
        for (int jb = 0; jb < 2; ++jb)
            vb[jb] = *(const short8*)&vTw[(jb * 16 + lr) * VT_STRIDE + ks * 32 + lk * 8];
#pragma unroll
        for (int i = 0; i < 4; ++i)
#pragma unroll
            for (int jb = 0; jb < 2; ++jb)
                o[i][jb] = __builtin_amdgcn_mfma_f32_16x16x32_bf16(vb[jb], pa[i], o[i][jb], 0, 0, 0);
    }

    // write attn output (bf16) as [b*49+n][h*32+d]; n = i*16+lr, d = jb*16+lk*4+(0..3)
    const size_t obase = (size_t)b * 49 * 512 + h * 32;
#pragma unroll
    for (int i = 0; i < 4; ++i) {
        const int n = i * 16 + lr;
        if (n < 49) {
#pragma unroll
            for (int jb = 0; jb < 2; ++jb) {
                ushort4v ov;
                ov.x = f2bf(o[i][jb][0]); ov.y = f2bf(o[i][jb][1]);
                ov.z = f2bf(o[i][jb][2]); ov.w = f2bf(o[i][jb][3]);
                *(ushort4v*)&out[obase + (size_t)n * 512 + jb * 16 + lk * 4] = ov;
            }
        }
    }
}

// ---------- launch ----------
extern "C" void kernel_launch(void* const* d_in, const int* in_sizes, int n_in,
                              void* d_out, int out_size, void* d_ws, size_t ws_size,
                              hipStream_t stream)
{
    const float* x         = (const float*)d_in[0];
    const float* mask      = (const float*)d_in[1];
    const float* qkv_w     = (const float*)d_in[2];
    const float* qkv_b     = (const float*)d_in[3];
    const float* proj_w    = (const float*)d_in[4];
    const float* proj_b    = (const float*)d_in[5];
    const float* rel_table = (const float*)d_in[6];
    const int*   rel_index = (const int*)d_in[7];

    char* ws = (char*)d_ws;
    ushort_t* xb  = (ushort_t*)ws;                      // x bf16 / attn-out reuse: 102,760,448 B
    ushort_t* qkv = (ushort_t*)(ws + 102760448);        // 308,281,344 B
    ushort_t* wtq = (ushort_t*)(ws + 411041792);        // 1,572,864 B
    ushort_t* wtp = (ushort_t*)(ws + 412614656);        // 524,288 B
    float*    cm  = (float*)  (ws + 413138944);         // 16,777,216 B (total ~430 MB)

    conv_x_kernel<<<50176, 256, 0, stream>>>(x, xb);
    prep_weights<<<3072, 256, 0, stream>>>(qkv_w, proj_w, wtq, wtp);
    build_cm<<<16384, 256, 0, stream>>>(mask, rel_table, rel_index, cm);

    // QKV GEMM: [100352,512] x [512,1536] -> qkv bf16 (q pre-scaled); 392x6 tiles
    gemm8<6, 1536, true, 512><<<2352, 512, 0, stream>>>(xb, wtq, qkv_b, qkv);

    // attention: grid (window fast, head, image-group), 4 waves/block
    attn_kernel<<<dim3(64, 16, 8), 256, 0, stream>>>(qkv, cm, xb);

    // proj GEMM: [100352,512] x [512,512] -> d_out f32; 392x2 tiles
    gemm8<2, 512, false, 512><<<784, 512, 0, stream>>>(xb, wtp, proj_b, d_out);
}

// Round 7
// 633.781 us; speedup vs baseline: 1.1045x; 1.0160x over previous
//
#include <hip/hip_runtime.h>

typedef unsigned short ushort_t;
typedef short short8 __attribute__((ext_vector_type(8)));
typedef float f32x4 __attribute__((ext_vector_type(4)));
typedef unsigned short ushort4v __attribute__((ext_vector_type(4)));

// ---------- helpers ----------
__device__ __forceinline__ ushort_t f2bf(float f) {
    unsigned int u = __float_as_uint(f);
    u = (u + 0x7fffu + ((u >> 16) & 1u)) >> 16;
    return (ushort_t)u;
}

__device__ __forceinline__ void async16(void* lds, const void* g) {
    __builtin_amdgcn_global_load_lds(
        (const __attribute__((address_space(1))) unsigned int*)g,
        (__attribute__((address_space(3))) unsigned int*)lds, 16, 0, 0);
}

// ---------- prep kernels ----------
__global__ void conv_x_kernel(const float* __restrict__ in, ushort_t* __restrict__ out) {
    int i = blockIdx.x * 256 + threadIdx.x;      // grid sized exactly: 50176*256 = 12845056
    float4 v = ((const float4*)in)[i];
    ushort4v o;
    o.x = f2bf(v.x); o.y = f2bf(v.y); o.z = f2bf(v.z); o.w = f2bf(v.w);
    ((ushort4v*)out)[i] = o;
}

__global__ void prep_weights(const float* __restrict__ qkv_w, const float* __restrict__ proj_w,
                             ushort_t* __restrict__ wtq, ushort_t* __restrict__ wtp) {
    int o = blockIdx.x * 256 + threadIdx.x;      // grid 3072*256 = 786432
    if (o < 1536 * 512) {
        int n = o >> 9, k = o & 511;
        wtq[o] = f2bf(qkv_w[k * 1536 + n]);      // wtq[n][k] = W[k][n]
    }
    if (o < 512 * 512) {
        int n = o >> 9, k = o & 511;
        wtp[o] = f2bf(proj_w[k * 512 + n]);
    }
}

__global__ void build_cm(const float* __restrict__ mask, const float* __restrict__ rel_table,
                         const int* __restrict__ rel_index, float* __restrict__ cm) {
    int o = blockIdx.x * 256 + threadIdx.x;      // grid 16384*256 = 4194304 = 64*16*64*64
    int c = o & 63, r = (o >> 6) & 63, h = (o >> 12) & 15, w = o >> 16;
    float v = -30000.0f;
    if (r < 49 && c < 49)
        v = rel_table[rel_index[r * 49 + c] * 16 + h] + mask[w * 2401 + r * 49 + c];
    cm[o] = v;
}

// ---------- 256x256 bf16 MFMA GEMM, counted-vmcnt 2-deep pipeline ----------
// C[M][N] = A[M][K] * Bt[N][K]^T + bias. BM=BN=256, BK=64, 8 waves (2M x 4N),
// double-buffered LDS (128 KiB, 1 block/CU).
// r7 fix: NEVER drain vmcnt to 0 in the main loop (T4). Prologue stages T0+T1
// (16 loads/thread in flight). Per tile: vmcnt(8) waits only this tile's 8
// loads (next tile's stay in flight) + barrier -> ds_reads + 64 MFMA (operand
// reuse: bf held whole tile, af per M-half; 24 b128/wave) -> barrier -> issue
// STAGE(T_{t+2}) into the next tile's shadow. vmcnt(0) only in the peeled
// last tile. WAR: stage issued after the read-complete barrier. RAW: per-wave
// vmcnt + following barrier makes all waves' loads globally visible.
// LDS swizzle: 16B-chunk index XOR (row&7), both sides (r5-verified, 0 confl).

#define STAGE(ldsbase, gbase) do {                                              \
    _Pragma("unroll")                                                           \
    for (int j_ = 0; j_ < 2; ++j_) {                                            \
        const int idx_ = j_ * 512 + tid;                                        \
        const int row_ = idx_ >> 3;                                             \
        const int sc_  = (((idx_ & 7) ^ (row_ & 7)) << 3);                      \
        async16((char*)(ldsbase) + idx_ * 16, (gbase) + (size_t)row_ * K + sc_);\
    }                                                                           \
} while (0)

#define VM8 asm volatile("s_waitcnt vmcnt(8)" ::: "memory")
#define VM0 asm volatile("s_waitcnt vmcnt(0)" ::: "memory")

#define LOADA(buf, mh) do {                                                     \
    _Pragma("unroll")                                                           \
    for (int f_ = 0; f_ < 4; ++f_) {                                            \
        const int ar_ = wr + ((mh) * 4 + f_) * 16 + lr;                         \
        _Pragma("unroll")                                                       \
        for (int ks_ = 0; ks_ < 2; ++ks_)                                       \
            af[f_][ks_] = *(const short8*)&As[buf][ar_ * 64 + ((ks_ * 32 + lk * 8) ^ ((ar_ & 7) << 3))]; \
    }                                                                           \
} while (0)

#define LOADB(buf) do {                                                         \
    _Pragma("unroll")                                                           \
    for (int g_ = 0; g_ < 4; ++g_) {                                            \
        const int br_ = wc + g_ * 16 + lr;                                      \
        _Pragma("unroll")                                                       \
        for (int ks_ = 0; ks_ < 2; ++ks_)                                       \
            bf[g_][ks_] = *(const short8*)&Bs[buf][br_ * 64 + ((ks_ * 32 + lk * 8) ^ ((br_ & 7) << 3))]; \
    }                                                                           \
} while (0)

#define LGKM0 do {                                                              \
    asm volatile("s_waitcnt lgkmcnt(0)" ::: "memory");                          \
    __builtin_amdgcn_sched_barrier(0);                                          \
} while (0)

#define MFMAH(mh) do {                                                          \
    __builtin_amdgcn_s_setprio(1);                                              \
    _Pragma("unroll")                                                           \
    for (int f_ = 0; f_ < 4; ++f_)                                              \
        _Pragma("unroll")                                                       \
        for (int g_ = 0; g_ < 4; ++g_)                                          \
            _Pragma("unroll")                                                   \
            for (int ks_ = 0; ks_ < 2; ++ks_)                                   \
                acc[(mh) * 4 + f_][g_] = __builtin_amdgcn_mfma_f32_16x16x32_bf16( \
                    bf[g_][ks_], af[f_][ks_], acc[(mh) * 4 + f_][g_], 0, 0, 0); \
    __builtin_amdgcn_s_setprio(0);                                              \
} while (0)

// One K-tile of the pipeline. VMWAIT: VM8 (steady) / VM0 (last). DOSTAGE:
// compile-time; stages tile at koff into THIS buf after the read barrier.
#define TILE(buf, VMWAIT, DOSTAGE, koff) do {                                   \
    VMWAIT;                                                                     \
    __builtin_amdgcn_s_barrier();   /* buf ready (all waves' loads done) */     \
    short8 af[4][2], bf[4][2];                                                  \
    LOADB(buf); LOADA(buf, 0);                                                  \
    LGKM0;                                                                      \
    MFMAH(0);                                                                   \
    LOADA(buf, 1);                                                              \
    LGKM0;                                                                      \
    MFMAH(1);                                                                   \
    __builtin_amdgcn_s_barrier();   /* all waves done READING buf */            \
    if (DOSTAGE) {                                                              \
        STAGE(&As[buf][0],    A  + a0 + (koff));                                \
        STAGE(&As[buf][8192], A  + a1 + (koff));                                \
        STAGE(&Bs[buf][0],    Bt + b0 + (koff));                                \
        STAGE(&Bs[buf][8192], Bt + b1 + (koff));                                \
    }                                                                           \
} while (0)

template<int NB_N, int NSTR, bool QKV, int K>
__global__ __launch_bounds__(512, 2)
void gemm8(const ushort_t* __restrict__ A, const ushort_t* __restrict__ Bt,
           const float* __restrict__ bias, void* __restrict__ out)
{
    __shared__ alignas(16) ushort_t As[2][256 * 64];   // 64 KiB
    __shared__ alignas(16) ushort_t Bs[2][256 * 64];   // 64 KiB

    const int tid = threadIdx.x;
    const int wid = tid >> 6, lane = tid & 63;
    const int lr = lane & 15, lk = lane >> 4;
    const int wr = (wid >> 2) * 128;     // 0 / 128
    const int wc = (wid & 3) * 64;       // 0..192

    // XCD-aware bijective swizzle (grid % 8 == 0 for both GEMMs)
    const int chunk = gridDim.x >> 3;
    const int wg = ((int)blockIdx.x & 7) * chunk + ((int)blockIdx.x >> 3);
    const int nb = wg % NB_N;
    const int mb = wg / NB_N;
    const int m0 = mb << 8, n0 = nb << 8;

    const size_t a0 = (size_t)m0 * K;
    const size_t a1 = (size_t)(m0 + 128) * K;
    const size_t b0 = (size_t)n0 * K;
    const size_t b1 = (size_t)(n0 + 128) * K;

    f32x4 acc[8][4];
#pragma unroll
    for (int f = 0; f < 8; ++f)
#pragma unroll
        for (int g = 0; g < 4; ++g)
#pragma unroll
            for (int r = 0; r < 4; ++r) acc[f][g][r] = 0.f;

    // prologue: T0 -> buf0, T1 -> buf1; 16 loads/thread in flight, NO drain
    STAGE(&As[0][0],    A  + a0);
    STAGE(&As[0][8192], A  + a1);
    STAGE(&Bs[0][0],    Bt + b0);
    STAGE(&Bs[0][8192], Bt + b1);
    STAGE(&As[1][0],    A  + a0 + 64);
    STAGE(&As[1][8192], A  + a1 + 64);
    STAGE(&Bs[1][0],    Bt + b0 + 64);
    STAGE(&Bs[1][8192], Bt + b1 + 64);

    const int KT = K >> 6;   // K-tiles; 8 for K=512 (even, >= 4)
    for (int t = 0; t < KT - 2; t += 2) {
        TILE(0, VM8, true, (t + 2) << 6);   // compute tile t,   stage t+2 -> buf0
        TILE(1, VM8, true, (t + 3) << 6);   // compute tile t+1, stage t+3 -> buf1
    }
    TILE(0, VM8, false, 0);                 // tile KT-2 (T_{KT-1} stays in flight)
    TILE(1, VM0, false, 0);                 // tile KT-1 (final drain)

    // epilogue: row = m0+wr+f*16+lr, cols = n0+wc+g*16+lk*4 + (0..3)
#pragma unroll
    for (int f = 0; f < 8; ++f) {
        const int row = m0 + wr + f * 16 + lr;
#pragma unroll
        for (int g = 0; g < 4; ++g) {
            const int col = n0 + wc + g * 16 + lk * 4;
            const float4 bv = *(const float4*)&bias[col];
            float v0 = acc[f][g][0] + bv.x;
            float v1 = acc[f][g][1] + bv.y;
            float v2 = acc[f][g][2] + bv.z;
            float v3 = acc[f][g][3] + bv.w;
            if (QKV) {
                if (col < 512) {   // q pre-scale (uniform per 4-col block)
                    v0 *= 0.17677669529663689f; v1 *= 0.17677669529663689f;
                    v2 *= 0.17677669529663689f; v3 *= 0.17677669529663689f;
                }
                ushort4v o;
                o.x = f2bf(v0); o.y = f2bf(v1); o.z = f2bf(v2); o.w = f2bf(v3);
                *(ushort4v*)&((ushort_t*)out)[(size_t)row * NSTR + col] = o;
            } else {
                float4 o; o.x = v0; o.y = v1; o.z = v2; o.w = v3;
                *(float4*)&((float*)out)[(size_t)row * NSTR + col] = o;
            }
        }
    }
}

// ---------- fused window attention: one wave per (b,h) ----------
// qkv: [100352][1536] bf16 (q pre-scaled, bias added). cm: [64][16][64][64] f32.
// out: [100352][512] bf16  (out[b*49+n][h*32+d])
#define PL_STRIDE 80   // bf16 elems; 160B rows -> 16B aligned
#define VT_STRIDE 88   // bf16 elems; 176B rows -> 16B aligned, low bank conflict
__global__ __launch_bounds__(256, 2)
void attn_kernel(const ushort_t* __restrict__ qkv, const float* __restrict__ cm,
                 ushort_t* __restrict__ out)
{
    // Pl region (40960B) is unioned with the cm tile (16640B); vT separate (22528B).
    __shared__ alignas(16) char smem[4 * 64 * PL_STRIDE * 2 + 4 * 32 * VT_STRIDE * 2];
    float* cmf = (float*)smem;                                    // [64][65]
    ushort_t* Pl = (ushort_t*)smem;                               // [4][64][PL_STRIDE]
    ushort_t* vT = (ushort_t*)(smem + 4 * 64 * PL_STRIDE * 2);    // [4][32][VT_STRIDE]

    const int w = blockIdx.x, h = blockIdx.y, ig = blockIdx.z;    // r1 grid (w fastest)
    const int tid = threadIdx.x;
    const int wid = tid >> 6, lane = tid & 63;
    const int lr = lane & 15, lk = lane >> 4;
    const int b = (ig * 4 + wid) * 64 + w;       // b % 64 == w (mask window index)

    // stage cm[w][h] tile into LDS (shared by the 4 waves)
    const float* cmsrc = cm + ((size_t)(w * 16 + h) << 12);
    for (int t = tid; t < 4096; t += 256)
        cmf[(t >> 6) * 65 + (t & 63)] = cmsrc[t];
    __syncthreads();

    const size_t base = (size_t)b * 49 * 1536 + h * 32;

    // q/k fragments (rows padded 49->64 via clamp; garbage killed by cm = -30000)
    short8 aq[4], bk[4];
#pragma unroll
    for (int i = 0; i < 4; ++i) {
        int n = i * 16 + lr; n = n > 48 ? 48 : n;
        aq[i] = *(const short8*)&qkv[base + (size_t)n * 1536 + lk * 8];
    }
#pragma unroll
    for (int j = 0; j < 4; ++j) {
        int m = j * 16 + lr; m = m > 48 ? 48 : m;
        bk[j] = *(const short8*)&qkv[base + 512 + (size_t)m * 1536 + lk * 8];
    }

    f32x4 s[4][4];
#pragma unroll
    for (int i = 0; i < 4; ++i)
#pragma unroll
        for (int j = 0; j < 4; ++j)
#pragma unroll
            for (int r = 0; r < 4; ++r) s[i][j][r] = 0.f;
#pragma unroll
    for (int i = 0; i < 4; ++i)
#pragma unroll
        for (int j = 0; j < 4; ++j)
            s[i][j] = __builtin_amdgcn_mfma_f32_16x16x32_bf16(aq[i], bk[j], s[i][j], 0, 0, 0);

    // v load (row m = lane) and transposed LDS store vT[d][m]
    short8 vv[4];
#pragma unroll
    for (int t = 0; t < 4; ++t)
#pragma unroll
        for (int e = 0; e < 8; ++e) vv[t][e] = 0;
    if (lane < 49) {
        const ushort_t* vp = &qkv[base + 1024 + (size_t)lane * 1536];
#pragma unroll
        for (int t = 0; t < 4; ++t) vv[t] = *(const short8*)(vp + t * 8);
    }
    ushort_t* vTw = vT + wid * 32 * VT_STRIDE;
#pragma unroll
    for (int t = 0; t < 4; ++t)
#pragma unroll
        for (int e = 0; e < 8; ++e)
            vTw[(t * 8 + e) * VT_STRIDE + lane] = (ushort_t)vv[t][e];

    // add bias+mask, wave-parallel softmax (rows are (lk*4+r)+16i, cols lane-spread)
#pragma unroll
    for (int i = 0; i < 4; ++i) {
#pragma unroll
        for (int r = 0; r < 4; ++r) {
            const int row = i * 16 + lk * 4 + r;
            float v0 = s[i][0][r] + cmf[row * 65 + lr];
            float v1 = s[i][1][r] + cmf[row * 65 + 16 + lr];
            float v2 = s[i][2][r] + cmf[row * 65 + 32 + lr];
            float v3 = s[i][3][r] + cmf[row * 65 + 48 + lr];
            float mx = fmaxf(fmaxf(v0, v1), fmaxf(v2, v3));
#pragma unroll
            for (int t = 1; t < 16; t <<= 1) mx = fmaxf(mx, __shfl_xor(mx, t, 64));
            v0 = __expf(v0 - mx); v1 = __expf(v1 - mx);
            v2 = __expf(v2 - mx); v3 = __expf(v3 - mx);
            float sm = v0 + v1 + v2 + v3;
#pragma unroll
            for (int t = 1; t < 16; t <<= 1) sm += __shfl_xor(sm, t, 64);
            const float inv = 1.0f / sm;
            s[i][0][r] = v0 * inv; s[i][1][r] = v1 * inv;
            s[i][2][r] = v2 * inv; s[i][3][r] = v3 * inv;
        }
    }
    __syncthreads();   // all waves done reading cm tile; safe to overwrite with P

    // P -> bf16 -> LDS (per-wave slice)
    ushort_t* Pw = Pl + wid * 64 * PL_STRIDE;
#pragma unroll
    for (int i = 0; i < 4; ++i)
#pragma unroll
        for (int j = 0; j < 4; ++j)
#pragma unroll
            for (int r = 0; r < 4; ++r)
                Pw[(i * 16 + lk * 4 + r) * PL_STRIDE + j * 16 + lr] = f2bf(s[i][j][r]);

    // PV: out[n][d] = sum_m P[n][m] * v[m][d]; operands swapped so each lane
    // holds 4 consecutive d for one n -> packed 8B stores.
    f32x4 o[4][2];
#pragma unroll
    for (int i = 0; i < 4; ++i)
#pragma unroll
        for (int jb = 0; jb < 2; ++jb)
#pragma unroll
            for (int r = 0; r < 4; ++r) o[i][jb][r] = 0.f;
#pragma unroll
    for (int ks = 0; ks < 2; ++ks) {
        short8 pa[4], vb[2];
#pragma unroll
        for (int i = 0; i < 4; ++i)
            pa[i] = *(const short8*)&Pw[(i * 16 + lr) * PL_STRIDE + ks * 32 + lk * 8];
#pragma unroll
        for (int jb = 0; jb < 2; ++jb)
            vb[jb] = *(const short8*)&vTw[(jb * 16 + lr) * VT_STRIDE + ks * 32 + lk * 8];
#pragma unroll
        for (int i = 0; i < 4; ++i)
#pragma unroll
            for (int jb = 0; jb < 2; ++jb)
                o[i][jb] = __builtin_amdgcn_mfma_f32_16x16x32_bf16(vb[jb], pa[i], o[i][jb], 0, 0, 0);
    }

    // write attn output (bf16) as [b*49+n][h*32+d]; n = i*16+lr, d = jb*16+lk*4+(0..3)
    const size_t obase = (size_t)b * 49 * 512 + h * 32;
#pragma unroll
    for (int i = 0; i < 4; ++i) {
        const int n = i * 16 + lr;
        if (n < 49) {
#pragma unroll
            for (int jb = 0; jb < 2; ++jb) {
                ushort4v ov;
                ov.x = f2bf(o[i][jb][0]); ov.y = f2bf(o[i][jb][1]);
                ov.z = f2bf(o[i][jb][2]); ov.w = f2bf(o[i][jb][3]);
                *(ushort4v*)&out[obase + (size_t)n * 512 + jb * 16 + lk * 4] = ov;
            }
        }
    }
}

// ---------- launch ----------
extern "C" void kernel_launch(void* const* d_in, const int* in_sizes, int n_in,
                              void* d_out, int out_size, void* d_ws, size_t ws_size,
                              hipStream_t stream)
{
    const float* x         = (const float*)d_in[0];
    const float* mask      = (const float*)d_in[1];
    const float* qkv_w     = (const float*)d_in[2];
    const float* qkv_b     = (const float*)d_in[3];
    const float* proj_w    = (const float*)d_in[4];
    const float* proj_b    = (const float*)d_in[5];
    const float* rel_table = (const float*)d_in[6];
    const int*   rel_index = (const int*)d_in[7];

    char* ws = (char*)d_ws;
    ushort_t* xb  = (ushort_t*)ws;                      // x bf16 / attn-out reuse: 102,760,448 B
    ushort_t* qkv = (ushort_t*)(ws + 102760448);        // 308,281,344 B
    ushort_t* wtq = (ushort_t*)(ws + 411041792);        // 1,572,864 B
    ushort_t* wtp = (ushort_t*)(ws + 412614656);        // 524,288 B
    float*    cm  = (float*)  (ws + 413138944);         // 16,777,216 B (total ~430 MB)

    conv_x_kernel<<<50176, 256, 0, stream>>>(x, xb);
    prep_weights<<<3072, 256, 0, stream>>>(qkv_w, proj_w, wtq, wtp);
    build_cm<<<16384, 256, 0, stream>>>(mask, rel_table, rel_index, cm);

    // QKV GEMM: [100352,512] x [512,1536] -> qkv bf16 (q pre-scaled); 392x6 tiles
    gemm8<6, 1536, true, 512><<<2352, 512, 0, stream>>>(xb, wtq, qkv_b, qkv);

    // attention: grid (window fast, head, image-group), 4 waves/block
    attn_kernel<<<dim3(64, 16, 8), 256, 0, stream>>>(qkv, cm, xb);

    // proj GEMM: [100352,512] x [512,512] -> d_out f32; 392x2 tiles
    gemm8<2, 512, false, 512><<<784, 512, 0, stream>>>(xb, wtp, proj_b, d_out);
}